// Round 13
// baseline (3537.881 us; speedup 1.0000x reference)
//
#include <hip/hip_runtime.h>

#define N_USERS 100000
#define N_ITEMS 50000
#define N_NODES 150000
#define EMB 64
#define NNZ_TOT 4800000
#define BATCH_SZ 4096

#define BROWS 64                  // rows per bucket
#define NB 2344                   // ceil(150000/64)
#define CHUNKS 512
#define CHUNKE 9375               // NNZ_TOT / CHUNKS (exact)
#define SBUF 3072                 // LDS sort buffer (bucket mean 2048, ~22 sigma)
#define NT 10                     // column tiles of 16384 nodes (2 MB of table)
#define KBINS 640                 // NT * BROWS sort bins
#define BPS 641                   // binptr stride per bucket (+1 sentinel)
#define ACCW 67                   // padded LDS accumulator row (odd -> bank spread)
#define BIN_LDS (2 * NB * 4 + CHUNKE * 8)   // 93,752 B dynamic LDS for k_bin

typedef unsigned short u16;
typedef unsigned long long u64;

static __device__ __forceinline__ u16 f2bf(float f) {
    unsigned u = __float_as_uint(f);
    unsigned r = u + 0x7FFFu + ((u >> 16) & 1u);   // RNE
    return (u16)(r >> 16);
}
static __device__ __forceinline__ float bf2f(u16 h) {
    return __uint_as_float(((unsigned)h) << 16);
}

// ---------------- ego0 (bf16) = concat(user, item) ----------------
__global__ void k_init(const float* __restrict__ ue, const float* __restrict__ ie,
                       u16* __restrict__ ego) {
    size_t i = (size_t)blockIdx.x * blockDim.x + threadIdx.x;
    const size_t n4 = (size_t)N_NODES * EMB / 4;
    if (i >= n4) return;
    const size_t u4 = (size_t)N_USERS * EMB / 4;
    float4 v = (i < u4) ? ((const float4*)ue)[i] : ((const float4*)ie)[i - u4];
    ushort4 o;
    o.x = f2bf(v.x); o.y = f2bf(v.y); o.z = f2bf(v.z); o.w = f2bf(v.w);
    ((ushort4*)ego)[i] = o;
}

__global__ void k_zero(int* __restrict__ p, int n) {
    int i = blockIdx.x * blockDim.x + threadIdx.x;
    if (i < n) p[i] = 0;
}

// ---- per-chunk counting-sort into 64-row buckets, LDS-staged (coalesced writes) ----
__global__ __launch_bounds__(1024) void k_bin(const int* __restrict__ erow,
                                              const int* __restrict__ ecol,
                                              const float* __restrict__ eval_,
                                              int2* __restrict__ pairsA,
                                              int* __restrict__ off_t,     // [(NB+1)][CHUNKS]
                                              int* __restrict__ bucketCnt) {
    extern __shared__ int smem[];
    int*  hist = smem;                 // NB
    int*  fill = smem + NB;            // NB
    int2* buf  = (int2*)(smem + 2 * NB); // CHUNKE edges
    const int c = blockIdx.x;
    const int cbase = c * CHUNKE;
    const int tid = threadIdx.x;

    for (int i = tid; i < NB; i += 1024) hist[i] = 0;
    __syncthreads();

    for (int i = tid; i < CHUNKE; i += 1024)
        atomicAdd(&hist[erow[cbase + i] >> 6], 1);
    __syncthreads();

    if (tid < 64) {
        int carry = 0;
        for (int blk = 0; blk < (NB + 63) / 64; ++blk) {
            int idx = blk * 64 + tid;
            int v = (idx < NB) ? hist[idx] : 0;
            int s = v;
            #pragma unroll
            for (int o = 1; o < 64; o <<= 1) {
                int t = __shfl_up(s, o);
                if (tid >= o) s += t;
            }
            if (idx < NB) fill[idx] = s - v + carry;
            carry += __shfl(s, 63);
        }
    }
    __syncthreads();

    for (int i = tid; i < NB; i += 1024) {
        off_t[i * CHUNKS + c] = cbase + fill[i];
        atomicAdd(&bucketCnt[i], hist[i]);
    }
    if (tid == 0) off_t[NB * CHUNKS + c] = cbase + CHUNKE;
    __syncthreads();

    for (int i = tid; i < CHUNKE; i += 1024) {
        int e = cbase + i;
        int r = erow[e];
        int bb = r >> 6;
        int p = atomicAdd(&fill[bb], 1);
        int2 pr;
        pr.x = ((r & 63) << 18) | ecol[e];
        pr.y = __float_as_int(eval_[e]);
        buf[p] = pr;
    }
    __syncthreads();

    for (int i = tid; i < CHUNKE; i += 1024)
        pairsA[cbase + i] = buf[i];
}

// ---------------- scan bucket counts -> bucket_base[0..NB] ----------------
__global__ __launch_bounds__(1024) void k_bscan(const int* __restrict__ cnt,
                                                int* __restrict__ bbase) {
    __shared__ int lds[1024];
    const int tid = threadIdx.x;
    int vals[3];
    int local = 0;
    #pragma unroll
    for (int j = 0; j < 3; ++j) {
        int idx = tid * 3 + j;
        int v = (idx < NB) ? cnt[idx] : 0;
        vals[j] = local;
        local += v;
    }
    lds[tid] = local;
    __syncthreads();
    for (int off = 1; off < 1024; off <<= 1) {
        int t = (tid >= off) ? lds[tid - off] : 0;
        __syncthreads();
        lds[tid] += t;
        __syncthreads();
    }
    int excl = lds[tid] - local;
    #pragma unroll
    for (int j = 0; j < 3; ++j) {
        int idx = tid * 3 + j;
        if (idx <= NB) bbase[idx] = excl + vals[j];
    }
}

// ---- per-bucket LDS sort by (col-tile, row_local) -> tiled CSR + binptr ----
__global__ __launch_bounds__(256) void k_sort(const int* __restrict__ off_t,
                                              const int2* __restrict__ pairsA,
                                              const int* __restrict__ bbase,
                                              int2* __restrict__ pairsB,
                                              int* __restrict__ binptr) {
    __shared__ int hist[KBINS];
    __shared__ int fillx[KBINS];
    __shared__ int2 buf[SBUF];
    __shared__ int wsum[4];
    const int b = blockIdx.x;
    const int tid = threadIdx.x, lane = tid & 63, w = tid >> 6;

    const int s0 = off_t[b * CHUNKS + tid];
    const int e0 = off_t[(b + 1) * CHUNKS + tid];
    const int s1 = off_t[b * CHUNKS + tid + 256];
    const int e1 = off_t[(b + 1) * CHUNKS + tid + 256];
    const int l0 = e0 - s0;
    const int len = l0 + (e1 - s1);

    for (int i = tid; i < KBINS; i += 256) hist[i] = 0;

    int sc = len;
    #pragma unroll
    for (int o = 1; o < 64; o <<= 1) {
        int t = __shfl_up(sc, o);
        if (lane >= o) sc += t;
    }
    if (lane == 63) wsum[w] = sc;
    __syncthreads();
    int wbase = 0;
    for (int i = 0; i < w; ++i) wbase += wsum[i];
    int tbase = wbase + sc - len;

    // key = tile*64 + row_local
    for (int i = 0; i < len; ++i) {
        int2 p = (i < l0) ? pairsA[s0 + i] : pairsA[s1 + (i - l0)];
        int dst = tbase + i;
        if (dst < SBUF) buf[dst] = p;
        int key = (((p.x & 0x3FFFF) >> 14) << 6) | (p.x >> 18);
        atomicAdd(&hist[key], 1);
    }
    __syncthreads();

    const int base = bbase[b];
    if (tid < 64) {
        int carry = 0;
        for (int blk = 0; blk < NT; ++blk) {
            int idx = blk * 64 + tid;
            int v = hist[idx];
            int s2 = v;
            #pragma unroll
            for (int o = 1; o < 64; o <<= 1) {
                int t = __shfl_up(s2, o);
                if (tid >= o) s2 += t;
            }
            int excl = s2 - v + carry;
            fillx[idx] = excl;
            binptr[(size_t)b * BPS + idx] = base + excl;
            carry += __shfl(s2, 63);
        }
        if (tid == 0) binptr[(size_t)b * BPS + KBINS] = bbase[b + 1];
    }
    __syncthreads();

    int total = bbase[b + 1] - base;
    if (total > SBUF) total = SBUF;
    for (int i = tid; i < total; i += 256) {
        int2 p = buf[i];
        int key = (((p.x & 0x3FFFF) >> 14) << 6) | (p.x >> 18);
        int pos = atomicAdd(&fillx[key], 1);
        pairsB[base + pos] = p;               // keep row_local bits
    }
}

// ---- SpMV: block per bucket, col-tile-ordered edges, f32 LDS accumulator ----
__global__ __launch_bounds__(256) void k_spmv(const int* __restrict__ binptr,
                                              const int2* __restrict__ pairs,
                                              const u16* __restrict__ cur,
                                              u16* __restrict__ nxt) {
    __shared__ float acc[BROWS][ACCW];
    const int b = blockIdx.x;
    const int tid = threadIdx.x;
    const int lane = tid & 63, w = tid >> 6;
    const int sl = lane & 31;
    const bool hi = lane >= 32;
    const unsigned sl4 = (unsigned)sl << 2;
    const char* tab = (const char*)cur;
    const u64* p8 = (const u64*)pairs;

    for (int i = tid; i < BROWS * ACCW; i += 256) ((float*)acc)[i] = 0.f;
    __syncthreads();

    const int* bp = binptr + (size_t)b * BPS;

#define PROC(q)                                                                \
    {                                                                          \
        unsigned x = (unsigned)(q);                                            \
        unsigned col = x & 0x3FFFFu;                                           \
        int rl = (int)(x >> 18);                                               \
        float v = __uint_as_float((unsigned)((q) >> 32));                      \
        unsigned u = *(const unsigned*)(tab + (size_t)((col << 7) | sl4));     \
        atomicAdd(&acc[rl][sl * 2],     v * __uint_as_float(u << 16));         \
        atomicAdd(&acc[rl][sl * 2 + 1], v * __uint_as_float(u & 0xFFFF0000u)); \
    }

    for (int t = 0; t < NT; ++t) {
        int s = bp[t * 64];
        int e = bp[(t + 1) * 64];
        int n = e - s;
        int per = (n + 3) >> 2;
        int ws = s + w * per;
        int we = ws + per; if (we > e) we = e;
        int m = we - ws; if (m < 0) m = 0;
        int half = m >> 1;
        int myb = hi ? (ws + half) : ws;
        int i = 0;
        for (; i + 3 < half; i += 4) {
            u64 q0 = p8[myb + i], q1 = p8[myb + i + 1];
            u64 q2 = p8[myb + i + 2], q3 = p8[myb + i + 3];
            PROC(q0) PROC(q1) PROC(q2) PROC(q3)
        }
        for (; i < half; ++i) {
            u64 q = p8[myb + i];
            PROC(q)
        }
        if (m & 1) {
            u64 q = p8[ws + m - 1];
            if (!hi) PROC(q)
        }
    }
#undef PROC
    __syncthreads();

    const int rbase = b * BROWS;
    for (int k = tid; k < BROWS * 32; k += 256) {
        int r = k >> 5, dl = k & 31;
        int node = rbase + r;
        if (node < N_NODES) {
            unsigned o = (unsigned)f2bf(acc[r][dl * 2])
                       | ((unsigned)f2bf(acc[r][dl * 2 + 1]) << 16);
            ((unsigned*)nxt)[(size_t)node * 32 + dl] = o;
        }
    }
}

// ---------------- out = layer-0 gather from f32 originals (exact) ----------------
__global__ void k_out0(const float* __restrict__ ue, const float* __restrict__ ie,
                       const int* __restrict__ users, const int* __restrict__ pos,
                       const int* __restrict__ neg, float* __restrict__ out) {
    size_t t = (size_t)blockIdx.x * blockDim.x + threadIdx.x;
    size_t r = t >> 4;
    int sub = (int)(t & 15);
    if (r >= (size_t)(3 * BATCH_SZ)) return;
    int which = (int)(r / BATCH_SZ);
    int bi    = (int)(r % BATCH_SZ);
    int node;
    if (which == 0)      node = users[bi];
    else if (which == 1) node = N_USERS + pos[bi];
    else                 node = N_USERS + neg[bi];
    const float* src = (node < N_USERS) ? (ue + (size_t)node * EMB)
                                        : (ie + (size_t)(node - N_USERS) * EMB);
    float4 v = ((const float4*)src)[sub];
    ((float4*)(out + r * EMB))[sub] = v;
}

// ---------------- out += layer-k gather (bf16) ----------------
__global__ void k_outb(const u16* __restrict__ ego,
                       const int* __restrict__ users, const int* __restrict__ pos,
                       const int* __restrict__ neg, float* __restrict__ out) {
    size_t t = (size_t)blockIdx.x * blockDim.x + threadIdx.x;
    size_t r = t >> 4;
    int sub = (int)(t & 15);
    if (r >= (size_t)(3 * BATCH_SZ)) return;
    int which = (int)(r / BATCH_SZ);
    int bi    = (int)(r % BATCH_SZ);
    int node;
    if (which == 0)      node = users[bi];
    else if (which == 1) node = N_USERS + pos[bi];
    else                 node = N_USERS + neg[bi];
    ushort4 h = ((const ushort4*)(ego + (size_t)node * EMB))[sub];
    float4* op = (float4*)(out + r * EMB) + sub;
    float4 o = *op;
    o.x += bf2f(h.x); o.y += bf2f(h.y); o.z += bf2f(h.z); o.w += bf2f(h.w);
    *op = o;
}

// ---- fused layer-3 spmv (batch rows only, walks NT row-bins) + final scale ----
__global__ __launch_bounds__(256) void k_last(const int* __restrict__ binptr,
                                              const int2* __restrict__ pairs,
                                              const u16* __restrict__ cur,
                                              const int* __restrict__ users,
                                              const int* __restrict__ pos,
                                              const int* __restrict__ neg,
                                              float* __restrict__ out) {
    size_t gid = (size_t)blockIdx.x * blockDim.x + threadIdx.x;
    int r    = (int)(gid >> 6);
    int lane = (int)(gid & 63);
    if (r >= 3 * BATCH_SZ) return;
    int which = r / BATCH_SZ;
    int bi    = r % BATCH_SZ;
    int node;
    if (which == 0)      node = users[bi];
    else if (which == 1) node = N_USERS + pos[bi];
    else                 node = N_USERS + neg[bi];
    const int bk = node >> 6, rl = node & 63;
    const int* bp = binptr + (size_t)bk * BPS;
    float a0 = 0.f, a1 = 0.f;
    for (int t = 0; t < NT; ++t) {
        int bin = t * 64 + rl;
        int s = bp[bin], e2 = bp[bin + 1];
        int e = s;
        for (; e + 1 < e2; e += 2) {
            int2 q0 = pairs[e], q1 = pairs[e + 1];
            float v0 = __uint_as_float((unsigned)q0.y);
            float v1 = __uint_as_float((unsigned)q1.y);
            a0 += v0 * bf2f(cur[(size_t)(q0.x & 0x3FFFF) * EMB + lane]);
            a1 += v1 * bf2f(cur[(size_t)(q1.x & 0x3FFFF) * EMB + lane]);
        }
        if (e < e2) {
            int2 q = pairs[e];
            float v = __uint_as_float((unsigned)q.y);
            a0 += v * bf2f(cur[(size_t)(q.x & 0x3FFFF) * EMB + lane]);
        }
    }
    size_t oi = (size_t)r * EMB + lane;
    out[oi] = (out[oi] + a0 + a1) * 0.25f;
}

extern "C" void kernel_launch(void* const* d_in, const int* in_sizes, int n_in,
                              void* d_out, int out_size, void* d_ws, size_t ws_size,
                              hipStream_t stream) {
    const int*   erow  = (const int*)  d_in[0];
    const int*   ecol  = (const int*)  d_in[1];
    const float* eval_ = (const float*)d_in[2];
    const float* ue    = (const float*)d_in[3];
    const float* ie    = (const float*)d_in[4];
    const int*   users = (const int*)  d_in[5];
    const int*   pos   = (const int*)  d_in[6];
    const int*   neg   = (const int*)  d_in[7];
    float* out = (float*)d_out;

    char* ws = (char*)d_ws;
    const size_t tblB  = (size_t)150016 * EMB * sizeof(u16);       // 19,202,048 B
    const size_t pairB = (size_t)NNZ_TOT * sizeof(int2);           // 38,400,000 B
    u16*  ego0   = (u16*)(ws);
    u16*  ego1   = (u16*)(ws + tblB);
    int2* pairsA = (int2*)(ws);                                    // aliases ego0/ego1
    int2* pairsB = (int2*)(ws + 2 * tblB);
    int*  off_t  = (int*) (ws + 2 * tblB + pairB);                 // (NB+1)*CHUNKS ints
    int*  binptr = off_t + (size_t)(NB + 1) * CHUNKS;              // NB*BPS+1 ints (~6 MB)
    int*  bucketCnt = binptr + (((size_t)NB * BPS + 1 + 63) & ~63ULL);
    int*  bbase     = bucketCnt + NB;

    const int blk = 256;

    hipFuncSetAttribute(reinterpret_cast<const void*>(k_bin),
                        hipFuncAttributeMaxDynamicSharedMemorySize, BIN_LDS);

    k_zero<<<(NB + blk - 1) / blk, blk, 0, stream>>>(bucketCnt, NB);
    k_bin<<<CHUNKS, 1024, BIN_LDS, stream>>>(erow, ecol, eval_, pairsA, off_t, bucketCnt);
    k_bscan<<<1, 1024, 0, stream>>>(bucketCnt, bbase);
    k_sort<<<NB, blk, 0, stream>>>(off_t, pairsA, bbase, pairsB, binptr);

    const size_t n4 = (size_t)N_NODES * EMB / 4;
    k_init<<<(int)((n4 + blk - 1) / blk), blk, 0, stream>>>(ue, ie, ego0);

    const int grid_g = (int)(((size_t)3 * BATCH_SZ * 16 + blk - 1) / blk);
    k_out0<<<grid_g, blk, 0, stream>>>(ue, ie, users, pos, neg, out);

    k_spmv<<<NB, blk, 0, stream>>>(binptr, pairsB, ego0, ego1);
    k_outb<<<grid_g, blk, 0, stream>>>(ego1, users, pos, neg, out);
    k_spmv<<<NB, blk, 0, stream>>>(binptr, pairsB, ego1, ego0);
    k_outb<<<grid_g, blk, 0, stream>>>(ego0, users, pos, neg, out);

    const size_t lth = (size_t)3 * BATCH_SZ * 64;
    k_last<<<(int)((lth + blk - 1) / blk), blk, 0, stream>>>(binptr, pairsB, ego0,
                                                             users, pos, neg, out);
}

// Round 14
// 423.071 us; speedup vs baseline: 8.3624x; 8.3624x over previous
//
#include <hip/hip_runtime.h>

#define N_USERS 100000
#define N_ITEMS 50000
#define N_NODES 150000
#define EMB 64
#define NNZ_TOT 4800000
#define BATCH_SZ 4096

#define BROWS 64                  // rows per bucket
#define NB 2344                   // ceil(150000/64)
#define CHUNKS 512
#define CHUNKE 9375               // NNZ_TOT / CHUNKS (exact)
#define SBUF 3072                 // LDS sort buffer (bucket mean 2048, ~22 sigma)
#define KBINS 2048                // sort key bins
#define BIN_LDS (2 * NB * 4 + CHUNKE * 8)   // 93,752 B dynamic LDS for k_bin

typedef unsigned short u16;

static __device__ __forceinline__ u16 f2bf(float f) {
    unsigned u = __float_as_uint(f);
    unsigned r = u + 0x7FFFu + ((u >> 16) & 1u);   // RNE
    return (u16)(r >> 16);
}
static __device__ __forceinline__ float bf2f(u16 h) {
    return __uint_as_float(((unsigned)h) << 16);
}

// ---------------- ego0 (bf16) = concat(user, item) ----------------
__global__ void k_init(const float* __restrict__ ue, const float* __restrict__ ie,
                       u16* __restrict__ ego) {
    size_t i = (size_t)blockIdx.x * blockDim.x + threadIdx.x;
    const size_t n4 = (size_t)N_NODES * EMB / 4;
    if (i >= n4) return;
    const size_t u4 = (size_t)N_USERS * EMB / 4;
    float4 v = (i < u4) ? ((const float4*)ue)[i] : ((const float4*)ie)[i - u4];
    ushort4 o;
    o.x = f2bf(v.x); o.y = f2bf(v.y); o.z = f2bf(v.z); o.w = f2bf(v.w);
    ((ushort4*)ego)[i] = o;
}

__global__ void k_zero(int* __restrict__ p, int n) {
    int i = blockIdx.x * blockDim.x + threadIdx.x;
    if (i < n) p[i] = 0;
}

// ---- per-chunk counting-sort into 64-row buckets, LDS-staged (coalesced writes) ----
__global__ __launch_bounds__(1024) void k_bin(const int* __restrict__ erow,
                                              const int* __restrict__ ecol,
                                              const float* __restrict__ eval_,
                                              int2* __restrict__ pairsA,
                                              int* __restrict__ off_t,     // [(NB+1)][CHUNKS]
                                              int* __restrict__ bucketCnt) {
    extern __shared__ int smem[];
    int*  hist = smem;                 // NB
    int*  fill = smem + NB;            // NB
    int2* buf  = (int2*)(smem + 2 * NB); // CHUNKE edges
    const int c = blockIdx.x;
    const int cbase = c * CHUNKE;
    const int tid = threadIdx.x;

    for (int i = tid; i < NB; i += 1024) hist[i] = 0;
    __syncthreads();

    for (int i = tid; i < CHUNKE; i += 1024)
        atomicAdd(&hist[erow[cbase + i] >> 6], 1);
    __syncthreads();

    if (tid < 64) {
        int carry = 0;
        for (int blk = 0; blk < (NB + 63) / 64; ++blk) {
            int idx = blk * 64 + tid;
            int v = (idx < NB) ? hist[idx] : 0;
            int s = v;
            #pragma unroll
            for (int o = 1; o < 64; o <<= 1) {
                int t = __shfl_up(s, o);
                if (tid >= o) s += t;
            }
            if (idx < NB) fill[idx] = s - v + carry;
            carry += __shfl(s, 63);
        }
    }
    __syncthreads();

    for (int i = tid; i < NB; i += 1024) {
        off_t[i * CHUNKS + c] = cbase + fill[i];
        atomicAdd(&bucketCnt[i], hist[i]);
    }
    if (tid == 0) off_t[NB * CHUNKS + c] = cbase + CHUNKE;
    __syncthreads();

    for (int i = tid; i < CHUNKE; i += 1024) {
        int e = cbase + i;
        int r = erow[e];
        int bb = r >> 6;
        int p = atomicAdd(&fill[bb], 1);
        int2 pr;
        pr.x = ((r & 63) << 18) | ecol[e];
        pr.y = __float_as_int(eval_[e]);
        buf[p] = pr;
    }
    __syncthreads();

    for (int i = tid; i < CHUNKE; i += 1024)
        pairsA[cbase + i] = buf[i];
}

// ---------------- scan bucket counts -> bucket_base[0..NB] ----------------
__global__ __launch_bounds__(1024) void k_bscan(const int* __restrict__ cnt,
                                                int* __restrict__ bbase,
                                                int* __restrict__ rowptr) {
    __shared__ int lds[1024];
    const int tid = threadIdx.x;
    int vals[3];
    int local = 0;
    #pragma unroll
    for (int j = 0; j < 3; ++j) {
        int idx = tid * 3 + j;
        int v = (idx < NB) ? cnt[idx] : 0;
        vals[j] = local;
        local += v;
    }
    lds[tid] = local;
    __syncthreads();
    for (int off = 1; off < 1024; off <<= 1) {
        int t = (tid >= off) ? lds[tid - off] : 0;
        __syncthreads();
        lds[tid] += t;
        __syncthreads();
    }
    int excl = lds[tid] - local;
    #pragma unroll
    for (int j = 0; j < 3; ++j) {
        int idx = tid * 3 + j;
        if (idx <= NB) {
            int b = excl + vals[j];
            bbase[idx] = b;
            if (idx == NB) rowptr[N_NODES] = b;   // == NNZ_TOT
        }
    }
}

// ---- per-bucket LDS sort by (row_local, col-tile) -> row-sorted CSR ----
__global__ __launch_bounds__(256) void k_sort(const int* __restrict__ off_t,
                                              const int2* __restrict__ pairsA,
                                              const int* __restrict__ bbase,
                                              int2* __restrict__ pairsB,
                                              int* __restrict__ rowptr) {
    __shared__ int hist[KBINS];
    __shared__ int fillx[KBINS];
    __shared__ int2 buf[SBUF];
    __shared__ int wsum[4];
    const int b = blockIdx.x;
    const int tid = threadIdx.x, lane = tid & 63, w = tid >> 6;

    const int s0 = off_t[b * CHUNKS + tid];
    const int e0 = off_t[(b + 1) * CHUNKS + tid];
    const int s1 = off_t[b * CHUNKS + tid + 256];
    const int e1 = off_t[(b + 1) * CHUNKS + tid + 256];
    const int l0 = e0 - s0;
    const int len = l0 + (e1 - s1);

    for (int i = tid; i < KBINS; i += 256) hist[i] = 0;

    int sc = len;
    #pragma unroll
    for (int o = 1; o < 64; o <<= 1) {
        int t = __shfl_up(sc, o);
        if (lane >= o) sc += t;
    }
    if (lane == 63) wsum[w] = sc;
    __syncthreads();
    int wbase = 0;
    for (int i = 0; i < w; ++i) wbase += wsum[i];
    int tbase = wbase + sc - len;

    for (int i = 0; i < len; ++i) {
        int2 p = (i < l0) ? pairsA[s0 + i] : pairsA[s1 + (i - l0)];
        int dst = tbase + i;
        if (dst < SBUF) buf[dst] = p;
        atomicAdd(&hist[(p.x >> 13) & (KBINS - 1)], 1);
    }
    __syncthreads();

    const int base = bbase[b];
    if (tid < 64) {
        int carry = 0;
        for (int blk = 0; blk < KBINS / 64; ++blk) {
            int idx = blk * 64 + tid;
            int v = hist[idx];
            int s2 = v;
            #pragma unroll
            for (int o = 1; o < 64; o <<= 1) {
                int t = __shfl_up(s2, o);
                if (tid >= o) s2 += t;
            }
            int excl = s2 - v + carry;
            fillx[idx] = excl;
            if ((idx & 31) == 0) {
                int node = b * BROWS + (idx >> 5);
                if (node < N_NODES) rowptr[node] = base + excl;
            }
            carry += __shfl(s2, 63);
        }
    }
    __syncthreads();

    int total = bbase[b + 1] - base;
    if (total > SBUF) total = SBUF;
    for (int i = tid; i < total; i += 256) {
        int2 p = buf[i];
        int pos = atomicAdd(&fillx[(p.x >> 13) & (KBINS - 1)], 1);
        pairsB[base + pos] = make_int2(p.x & 0x3FFFF, p.y);
    }
}

// ---- SpMV: 2 rows per wave; 2 edges per wave-gather; independent chains ----
__global__ __launch_bounds__(256) void k_spmv(const int* __restrict__ rowptr,
                                              const int2* __restrict__ pairs,
                                              const u16* __restrict__ cur,
                                              u16* __restrict__ nxt) {
    size_t gid = (size_t)blockIdx.x * blockDim.x + threadIdx.x;
    int pr   = (int)(gid >> 6);               // row pair index
    int lane = (int)(gid & 63);
    int rowA = pr * 2;
    if (rowA >= N_NODES) return;
    const int      sl  = lane & 31;
    const bool     hi  = lane >= 32;
    const unsigned sl4 = (unsigned)sl << 2;
    const char* tab = (const char*)cur;        // 128 B per row
    const int4* p4 = (const int4*)pairs;

    int sA = rowptr[rowA];
    int mA = rowptr[rowA + 1];                 // end A == start B
    int eBnd = rowptr[rowA + 2];

    float a0 = 0.f, a1 = 0.f, b0 = 0.f, b1 = 0.f;   // row A
    float c0 = 0.f, c1 = 0.f, d0 = 0.f, d1 = 0.f;   // row B

#define PROC1(q, x0, x1, pred)                                                 \
    {                                                                          \
        unsigned col = (unsigned)(q).x;                                        \
        float v = __uint_as_float((unsigned)(q).y);                            \
        unsigned u = *(const unsigned*)(tab + (size_t)((col << 7) | sl4));     \
        float vm = (pred) ? v : 0.f;                                           \
        x0 += vm * __uint_as_float(u << 16);                                   \
        x1 += vm * __uint_as_float(u & 0xFFFF0000u);                           \
    }
#define PROC(d, x0, x1)                                                        \
    {                                                                          \
        unsigned col = (unsigned)(hi ? (d).z : (d).x);                         \
        float    vv  = __uint_as_float((unsigned)(hi ? (d).w : (d).y));        \
        unsigned u = *(const unsigned*)(tab + (size_t)((col << 7) | sl4));     \
        x0 += vv * __uint_as_float(u << 16);                                   \
        x1 += vv * __uint_as_float(u & 0xFFFF0000u);                           \
    }

    int eA = sA, eB = mA;
    if ((eA & 1) && eA < mA)   { int2 q = pairs[eA]; PROC1(q, a0, a1, !hi) ++eA; }
    if ((eB & 1) && eB < eBnd) { int2 q = pairs[eB]; PROC1(q, c0, c1, !hi) ++eB; }

    // co-loop: 8 edges per row per iteration, two independent load chains
    while (eA + 7 < mA && eB + 7 < eBnd) {
        int hA = eA >> 1, hB = eB >> 1;
        int4 A0 = p4[hA + 0], A1 = p4[hA + 1], A2 = p4[hA + 2], A3 = p4[hA + 3];
        int4 B0 = p4[hB + 0], B1 = p4[hB + 1], B2 = p4[hB + 2], B3 = p4[hB + 3];
        PROC(A0, a0, a1) PROC(B0, c0, c1)
        PROC(A1, b0, b1) PROC(B1, d0, d1)
        PROC(A2, a0, a1) PROC(B2, c0, c1)
        PROC(A3, b0, b1) PROC(B3, d0, d1)
        eA += 8; eB += 8;
    }
    // row A remainder
    for (; eA + 7 < mA; eA += 8) {
        int h = eA >> 1;
        int4 q0 = p4[h + 0], q1 = p4[h + 1], q2 = p4[h + 2], q3 = p4[h + 3];
        PROC(q0, a0, a1) PROC(q1, b0, b1) PROC(q2, a0, a1) PROC(q3, b0, b1)
    }
    for (; eA + 1 < mA; eA += 2) {
        int4 d = p4[eA >> 1];
        PROC(d, a0, a1)
    }
    if (eA < mA) { int2 q = pairs[eA]; PROC1(q, a0, a1, !hi) }
    // row B remainder
    for (; eB + 7 < eBnd; eB += 8) {
        int h = eB >> 1;
        int4 q0 = p4[h + 0], q1 = p4[h + 1], q2 = p4[h + 2], q3 = p4[h + 3];
        PROC(q0, c0, c1) PROC(q1, d0, d1) PROC(q2, c0, c1) PROC(q3, d0, d1)
    }
    for (; eB + 1 < eBnd; eB += 2) {
        int4 d = p4[eB >> 1];
        PROC(d, c0, c1)
    }
    if (eB < eBnd) { int2 q = pairs[eB]; PROC1(q, c0, c1, !hi) }
#undef PROC
#undef PROC1

    float s0 = a0 + b0, s1 = a1 + b1;
    float t0 = c0 + d0, t1 = c1 + d1;
    s0 += __shfl_xor(s0, 32);
    s1 += __shfl_xor(s1, 32);
    t0 += __shfl_xor(t0, 32);
    t1 += __shfl_xor(t1, 32);
    if (!hi) {
        unsigned oA = (unsigned)f2bf(s0) | ((unsigned)f2bf(s1) << 16);
        unsigned oB = (unsigned)f2bf(t0) | ((unsigned)f2bf(t1) << 16);
        ((unsigned*)nxt)[(size_t)rowA * 32 + sl] = oA;
        ((unsigned*)nxt)[(size_t)(rowA + 1) * 32 + sl] = oB;
    }
}

// ---------------- out = layer-0 gather from f32 originals (exact) ----------------
__global__ void k_out0(const float* __restrict__ ue, const float* __restrict__ ie,
                       const int* __restrict__ users, const int* __restrict__ pos,
                       const int* __restrict__ neg, float* __restrict__ out) {
    size_t t = (size_t)blockIdx.x * blockDim.x + threadIdx.x;
    size_t r = t >> 4;
    int sub = (int)(t & 15);
    if (r >= (size_t)(3 * BATCH_SZ)) return;
    int which = (int)(r / BATCH_SZ);
    int bi    = (int)(r % BATCH_SZ);
    int node;
    if (which == 0)      node = users[bi];
    else if (which == 1) node = N_USERS + pos[bi];
    else                 node = N_USERS + neg[bi];
    const float* src = (node < N_USERS) ? (ue + (size_t)node * EMB)
                                        : (ie + (size_t)(node - N_USERS) * EMB);
    float4 v = ((const float4*)src)[sub];
    ((float4*)(out + r * EMB))[sub] = v;
}

// ---------------- out += layer-k gather (bf16) ----------------
__global__ void k_outb(const u16* __restrict__ ego,
                       const int* __restrict__ users, const int* __restrict__ pos,
                       const int* __restrict__ neg, float* __restrict__ out) {
    size_t t = (size_t)blockIdx.x * blockDim.x + threadIdx.x;
    size_t r = t >> 4;
    int sub = (int)(t & 15);
    if (r >= (size_t)(3 * BATCH_SZ)) return;
    int which = (int)(r / BATCH_SZ);
    int bi    = (int)(r % BATCH_SZ);
    int node;
    if (which == 0)      node = users[bi];
    else if (which == 1) node = N_USERS + pos[bi];
    else                 node = N_USERS + neg[bi];
    ushort4 h = ((const ushort4*)(ego + (size_t)node * EMB))[sub];
    float4* op = (float4*)(out + r * EMB) + sub;
    float4 o = *op;
    o.x += bf2f(h.x); o.y += bf2f(h.y); o.z += bf2f(h.z); o.w += bf2f(h.w);
    *op = o;
}

// ---------------- fused layer-3 spmv (batch rows only) + final scale ----------------
#define RFL(x) __builtin_amdgcn_readfirstlane(x)
__global__ __launch_bounds__(256) void k_last(const int* __restrict__ rowptr,
                                              const int2* __restrict__ pairs,
                                              const u16* __restrict__ cur,
                                              const int* __restrict__ users,
                                              const int* __restrict__ pos,
                                              const int* __restrict__ neg,
                                              float* __restrict__ out) {
    size_t gid = (size_t)blockIdx.x * blockDim.x + threadIdx.x;
    int r    = (int)(gid >> 6);
    int lane = (int)(gid & 63);
    if (r >= 3 * BATCH_SZ) return;
    int which = r / BATCH_SZ;
    int bi    = r % BATCH_SZ;
    int node;
    if (which == 0)      node = users[bi];
    else if (which == 1) node = N_USERS + pos[bi];
    else                 node = N_USERS + neg[bi];
    int start = rowptr[node];
    int end   = rowptr[node + 1];
    float a0 = 0.f, a1 = 0.f, a2 = 0.f, a3 = 0.f;
    int e = start;
    for (; e + 3 < end; e += 4) {
        int2 q0 = pairs[e], q1 = pairs[e + 1], q2 = pairs[e + 2], q3 = pairs[e + 3];
        int   c0 = RFL(q0.x);
        float v0 = __uint_as_float(RFL(q0.y));
        int   c1 = RFL(q1.x);
        float v1 = __uint_as_float(RFL(q1.y));
        int   c2 = RFL(q2.x);
        float v2 = __uint_as_float(RFL(q2.y));
        int   c3 = RFL(q3.x);
        float v3 = __uint_as_float(RFL(q3.y));
        a0 += v0 * bf2f(cur[(size_t)c0 * EMB + lane]);
        a1 += v1 * bf2f(cur[(size_t)c1 * EMB + lane]);
        a2 += v2 * bf2f(cur[(size_t)c2 * EMB + lane]);
        a3 += v3 * bf2f(cur[(size_t)c3 * EMB + lane]);
    }
    for (; e < end; ++e) {
        int2 q = pairs[e];
        int   c = RFL(q.x);
        float v = __uint_as_float(RFL(q.y));
        a0 += v * bf2f(cur[(size_t)c * EMB + lane]);
    }
    float sum = (a0 + a1) + (a2 + a3);
    size_t oi = (size_t)r * EMB + lane;
    out[oi] = (out[oi] + sum) * 0.25f;
}

extern "C" void kernel_launch(void* const* d_in, const int* in_sizes, int n_in,
                              void* d_out, int out_size, void* d_ws, size_t ws_size,
                              hipStream_t stream) {
    const int*   erow  = (const int*)  d_in[0];
    const int*   ecol  = (const int*)  d_in[1];
    const float* eval_ = (const float*)d_in[2];
    const float* ue    = (const float*)d_in[3];
    const float* ie    = (const float*)d_in[4];
    const int*   users = (const int*)  d_in[5];
    const int*   pos   = (const int*)  d_in[6];
    const int*   neg   = (const int*)  d_in[7];
    float* out = (float*)d_out;

    char* ws = (char*)d_ws;
    const size_t tblB  = (size_t)150016 * EMB * sizeof(u16);       // 19,202,048 B
    const size_t pairB = (size_t)NNZ_TOT * sizeof(int2);           // 38,400,000 B
    u16*  ego0   = (u16*)(ws);
    u16*  ego1   = (u16*)(ws + tblB);
    int2* pairsA = (int2*)(ws);                                    // aliases ego0/ego1
    int2* pairsB = (int2*)(ws + 2 * tblB);
    int*  off_t  = (int*) (ws + 2 * tblB + pairB);                 // (NB+1)*CHUNKS ints
    int*  rowptr = off_t + (size_t)(NB + 1) * CHUNKS;
    int*  bucketCnt = rowptr + ((N_NODES + 1 + 63) & ~63);
    int*  bbase     = bucketCnt + NB;

    const int blk = 256;

    hipFuncSetAttribute(reinterpret_cast<const void*>(k_bin),
                        hipFuncAttributeMaxDynamicSharedMemorySize, BIN_LDS);

    k_zero<<<(NB + blk - 1) / blk, blk, 0, stream>>>(bucketCnt, NB);
    k_bin<<<CHUNKS, 1024, BIN_LDS, stream>>>(erow, ecol, eval_, pairsA, off_t, bucketCnt);
    k_bscan<<<1, 1024, 0, stream>>>(bucketCnt, bbase, rowptr);
    k_sort<<<NB, blk, 0, stream>>>(off_t, pairsA, bbase, pairsB, rowptr);

    const size_t n4 = (size_t)N_NODES * EMB / 4;
    k_init<<<(int)((n4 + blk - 1) / blk), blk, 0, stream>>>(ue, ie, ego0);

    const int grid_g = (int)(((size_t)3 * BATCH_SZ * 16 + blk - 1) / blk);
    k_out0<<<grid_g, blk, 0, stream>>>(ue, ie, users, pos, neg, out);

    const size_t spmv_threads = (size_t)(N_NODES / 2) * 64;        // 2 rows per wave
    const int grid_spmv = (int)((spmv_threads + blk - 1) / blk);
    k_spmv<<<grid_spmv, blk, 0, stream>>>(rowptr, pairsB, ego0, ego1);
    k_outb<<<grid_g, blk, 0, stream>>>(ego1, users, pos, neg, out);
    k_spmv<<<grid_spmv, blk, 0, stream>>>(rowptr, pairsB, ego1, ego0);
    k_outb<<<grid_g, blk, 0, stream>>>(ego0, users, pos, neg, out);

    const size_t lth = (size_t)3 * BATCH_SZ * 64;
    k_last<<<(int)((lth + blk - 1) / blk), blk, 0, stream>>>(rowptr, pairsB, ego0,
                                                             users, pos, neg, out);
}